// Round 22
// baseline (711.526 us; speedup 1.0000x reference)
//
#include <hip/hip_runtime.h>

#define NSTEPS 20

typedef short bf16x8 __attribute__((ext_vector_type(8)));
typedef float f32x16 __attribute__((ext_vector_type(16)));

union B8 { bf16x8 h; unsigned u[4]; unsigned short s[8]; };

__device__ __forceinline__ unsigned short f2bf(float x) {
    unsigned u = __builtin_bit_cast(unsigned, x);
    u += 0x7fffu + ((u >> 16) & 1u);
    return (unsigned short)(u >> 16);
}
__device__ __forceinline__ float bf2f(unsigned short b) {
    return __builtin_bit_cast(float, (unsigned)b << 16);
}
__device__ __forceinline__ unsigned pk(unsigned short lo, unsigned short hi) {
    return (unsigned)lo | ((unsigned)hi << 16);
}
__device__ __forceinline__ unsigned cvtpk(float a, float b) {
    unsigned r;
    asm("v_cvt_pk_bf16_f32 %0, %1, %2" : "=v"(r) : "v"(a), "v"(b));
    return r;
}
__device__ __forceinline__ float lo_f(unsigned w) { return __builtin_bit_cast(float, w << 16); }
__device__ __forceinline__ float hi_f(unsigned w) { return __builtin_bit_cast(float, w & 0xffff0000u); }

#define MFMA(A, B, C) __builtin_amdgcn_mfma_f32_32x32x16_bf16((A), (B), (C), 0, 0, 0)
#define PRIO1() __builtin_amdgcn_s_setprio(1)
#define PRIO0() __builtin_amdgcn_s_setprio(0)

__device__ __forceinline__ void wlimbs(float w, unsigned short& l0, unsigned short& l1, unsigned short& l2) {
    l0 = f2bf(w); float e = w - bf2f(l0);
    l1 = f2bf(e); e -= bf2f(l1);
    l2 = f2bf(e);
}
__device__ __forceinline__ unsigned short pick(int m, unsigned short l0, unsigned short l1, unsigned short l2) {
    return (m == 0) ? l0 : ((m == 1) ? l1 : l2);
}

// ---------- A-fragment builders; k = 16*F_ + 4h + (j&3) + 8*(j>>2) ----------

template<int F_, int M>
__device__ __forceinline__ bf16x8 awide(const float* W, const float* bias, int nout, int ld, int lane)
{
    const int u = lane & 31, h = (lane >> 5) & 1;
    B8 r;
#pragma unroll
    for (int j = 0; j < 8; ++j) {
        const int k = 16 * F_ + 4 * h + (j & 3) + 8 * (j >> 2);
        float v = 0.f;
        if (u < nout) {
            if (k < 30) v = W[k * ld + u];
            else if (k == 30) v = bias[u];
        }
        unsigned short l0, l1, l2; wlimbs(v, l0, l1, l2);
        r.s[j] = (short)pick(M, l0, l1, l2);
    }
    return r.h;
}

template<int S, int F_>
__device__ __forceinline__ bf16x8 a5(const float* W, const float* bias, int lane)
{
    const int u = lane & 31, h = (lane >> 5) & 1;
    B8 r;
#pragma unroll
    for (int j = 0; j < 8; ++j) {
        const int k = 16 * F_ + 4 * h + (j & 3) + 8 * (j >> 2);
        unsigned short bits = 0;
        if (u < 30) {
            int in = -1, m = -1;
            if (F_ == 0) {
                if (k < 4)       { in = k; m = S; }
                else if (k == 4) { in = 4; m = S; }
            } else {
                if (k >= 16 && k < 20)      { in = k - 16; m = (S == 0) ? 1 : ((S == 1) ? 0 : -1); }
                else if (k == 20)           { in = 4;      m = (S == 0) ? 1 : ((S == 1) ? 0 : -1); }
                else if (k >= 24 && k < 28) { in = k - 24; m = (S == 0) ? 2 : ((S == 2) ? 0 : -1); }
                else if (k == 21)           { in = 4;      m = (S == 0) ? 2 : ((S == 2) ? 0 : -1); }
            }
            if (in >= 0 && m >= 0) {
                unsigned short l0, l1, l2; wlimbs(W[in * 30 + u], l0, l1, l2);
                bits = pick(m, l0, l1, l2);
            } else if (F_ == 0 && k == 15) {
                unsigned short l0, l1, l2; wlimbs(bias[u], l0, l1, l2);
                bits = pick(S, l0, l1, l2);
            }
        }
        r.s[j] = (short)bits;
    }
    return r.h;
}

template<int S>
__device__ __forceinline__ bf16x8 a1f(const float* W1, const float* b1v, int lane)
{
    const int perm[4] = {0, 3, 1, 2};
    const int u = lane & 31, h = (lane >> 5) & 1;
    B8 r;
#pragma unroll
    for (int j = 0; j < 8; ++j) {
        const int k = 4 * h + (j & 3) + 8 * (j >> 2);
        unsigned short bits = 0;
        if (u < 30) {
            int in = -1, m = -1;
            if (k < 4)       { in = k;     m = (S == 0) ? 0 : ((S == 1) ? 1 : 2); }
            else if (k < 8)  { in = k - 4; m = (S == 0) ? 1 : ((S == 1) ? 0 : -1); }
            else if (k < 12) { in = k - 8; m = (S == 0) ? 2 : ((S == 2) ? 0 : -1); }
            if (in >= 0 && m >= 0) {
                unsigned short l0, l1, l2; wlimbs(W1[perm[in] * 30 + u], l0, l1, l2);
                bits = pick(m, l0, l1, l2);
            } else if (k == 12) {
                unsigned short l0, l1, l2; wlimbs(b1v[u], l0, l1, l2);
                bits = pick(S, l0, l1, l2);
            }
        }
        r.s[j] = (short)bits;
    }
    return r.h;
}

// ---------- activation transitions (r15/r17/r18/r20/r21 exact) ----------

template<int LIMBS>
__device__ __forceinline__ void split_pair(float a, float b,
                                           unsigned& w0, unsigned& w1, unsigned& w2)
{
    w0 = cvtpk(a, b);
    if (LIMBS >= 2) {
        float e0 = a - lo_f(w0), e1 = b - hi_f(w0);
        w1 = cvtpk(e0, e1);
        if (LIMBS == 3) {
            float f0 = e0 - lo_f(w1), f1 = e1 - hi_f(w1);
            w2 = cvtpk(f0, f1);
        } else w2 = 0u;
    } else { w1 = 0u; w2 = 0u; }
}

template<int LIMBS>
__device__ __forceinline__ void split30(const f32x16& acc, bool hi,
                                        B8& B0a, B8& B0b, B8& B1a, B8& B1b,
                                        B8& B2a, B8& B2b)
{
#pragma unroll
    for (int i = 0; i < 4; ++i) {
        const float a = fmaxf(acc[2 * i], 0.f), b = fmaxf(acc[2 * i + 1], 0.f);
        unsigned w0, w1, w2; split_pair<LIMBS>(a, b, w0, w1, w2);
        B0a.u[i] = w0;
        if (LIMBS >= 2) B1a.u[i] = w1;
        if (LIMBS == 3) B2a.u[i] = w2;
    }
#pragma unroll
    for (int i = 0; i < 4; ++i) {
        const float a = fmaxf(acc[8 + 2 * i], 0.f), b = fmaxf(acc[8 + 2 * i + 1], 0.f);
        unsigned w0, w1, w2; split_pair<LIMBS>(a, b, w0, w1, w2);
        B0b.u[i] = w0;
        if (LIMBS >= 2) B1b.u[i] = w1;
        if (LIMBS == 3) B2b.u[i] = w2;
    }
    if (hi) {
        B0b.u[3] = 0x00003F80u;                 // k30 = 1.0 (bias input)
        if (LIMBS >= 2) B1b.u[3] = 0u;
        if (LIMBS == 3) B2b.u[3] = 0u;
    }
}

template<int LIMBS>
__device__ __forceinline__ void split5(const f32x16& acc, bool hi, B8& C0, B8& C1)
{
    const float a0 = acc[0], a1 = acc[1];
    const float a2 = acc[2], a3 = acc[3];
    unsigned p0, p1, p2, q0, q1, q2;
    split_pair<LIMBS>(a0, a1, p0, p1, p2);
    split_pair<LIMBS>(a2, a3, q0, q1, q2);
    if (!hi) {
        C0.u[0] = p0; C0.u[1] = q0; C0.u[2] = 0; C0.u[3] = 0;
        if (LIMBS >= 2) {
            C1.u[0] = p1; C1.u[1] = q1;
            C1.u[2] = (LIMBS == 3) ? p2 : 0u;
            C1.u[3] = (LIMBS == 3) ? q2 : 0u;
        }
    } else {
        C0.u[0] = p0 & 0xffffu;
        C0.u[1] = 0; C0.u[2] = 0;
        C0.u[3] = 0x3F800000u;                  // k15 = 1.0 (bias input)
        if (LIMBS >= 2) {
            C1.u[0] = (LIMBS == 3) ? pk((unsigned short)(p1 & 0xffffu), (unsigned short)(p2 & 0xffffu))
                                   : (p1 & 0xffffu);
            C1.u[1] = 0; C1.u[2] = 0; C1.u[3] = 0;
        }
    }
}

// LDS frag index map: 0-2 A1; 3-8 A2; 9-14 A3; 15-20 A4; 21-26 A5.
#define NFRAG 27

// Standalone MLP (r21 exact) — used in prologue (LIMBS=3) / epilogue (LIMBS=1).
template<int LIMBS>
__device__ __forceinline__ f32x16 evalnet5(
    float price, float f3, unsigned tT0, unsigned tT1, unsigned tT2,
    bool hi, const bf16x8* LF, int lane, const f32x16& Z)
{
    unsigned pf0, pf1, pf2;
    split_pair<LIMBS>(price, f3, pf0, pf1, pf2);
    B8 B;
    if (!hi) {
        B.u[0] = pf0; B.u[1] = tT0;
        B.u[2] = (LIMBS == 3) ? pf2 : 0u;
        B.u[3] = (LIMBS == 3) ? tT2 : 0u;
    } else {
        B.u[0] = (LIMBS >= 2) ? pf1 : 0u;
        B.u[1] = (LIMBS >= 2) ? tT1 : 0u;
        B.u[2] = 0x00003F80u;
        B.u[3] = 0u;
    }

    PRIO1();
    f32x16 acc = MFMA(LF[0 * 64 + lane], B.h, Z);
    if (LIMBS >= 2) acc = MFMA(LF[1 * 64 + lane], B.h, acc);
    if (LIMBS == 3) acc = MFMA(LF[2 * 64 + lane], B.h, acc);
    PRIO0();

    B8 B0a, B0b, B1a, B1b, B2a, B2b, C0, C1;
    f32x16 p, q;

    split30<LIMBS>(acc, hi, B0a, B0b, B1a, B1b, B2a, B2b);
    PRIO1();
    p = MFMA(LF[3 * 64 + lane], B0a.h, Z);
    q = MFMA(LF[4 * 64 + lane], B0b.h, Z);
    if (LIMBS >= 2) {
        p = MFMA(LF[3 * 64 + lane], B1a.h, p);
        q = MFMA(LF[4 * 64 + lane], B1b.h, q);
        if (LIMBS == 3) { p = MFMA(LF[3 * 64 + lane], B2a.h, p); q = MFMA(LF[4 * 64 + lane], B2b.h, q); }
        p = MFMA(LF[5 * 64 + lane], B0a.h, p);
        q = MFMA(LF[6 * 64 + lane], B0b.h, q);
        p = MFMA(LF[5 * 64 + lane], B1a.h, p);
        q = MFMA(LF[6 * 64 + lane], B1b.h, q);
        if (LIMBS == 3) { p = MFMA(LF[7 * 64 + lane], B0a.h, p); q = MFMA(LF[8 * 64 + lane], B0b.h, q); }
    }
    PRIO0();
    acc = p + q;

    split5<LIMBS>(acc, hi, C0, C1);
    PRIO1();
    if (LIMBS >= 2) {
        p = MFMA(LF[9 * 64 + lane], C0.h, Z);
        q = MFMA(LF[10 * 64 + lane], C1.h, Z);
        p = MFMA(LF[11 * 64 + lane], C0.h, p);
        q = MFMA(LF[12 * 64 + lane], C1.h, q);
        if (LIMBS == 3) { p = MFMA(LF[13 * 64 + lane], C0.h, p); q = MFMA(LF[14 * 64 + lane], C1.h, q); }
        acc = p + q;
    } else {
        acc = MFMA(LF[9 * 64 + lane], C0.h, Z);
    }
    PRIO0();

    split30<LIMBS>(acc, hi, B0a, B0b, B1a, B1b, B2a, B2b);
    PRIO1();
    p = MFMA(LF[15 * 64 + lane], B0a.h, Z);
    q = MFMA(LF[16 * 64 + lane], B0b.h, Z);
    if (LIMBS >= 2) {
        p = MFMA(LF[15 * 64 + lane], B1a.h, p);
        q = MFMA(LF[16 * 64 + lane], B1b.h, q);
        if (LIMBS == 3) { p = MFMA(LF[15 * 64 + lane], B2a.h, p); q = MFMA(LF[16 * 64 + lane], B2b.h, q); }
        p = MFMA(LF[17 * 64 + lane], B0a.h, p);
        q = MFMA(LF[18 * 64 + lane], B0b.h, q);
        p = MFMA(LF[17 * 64 + lane], B1a.h, p);
        q = MFMA(LF[18 * 64 + lane], B1b.h, q);
        if (LIMBS == 3) { p = MFMA(LF[19 * 64 + lane], B0a.h, p); q = MFMA(LF[20 * 64 + lane], B0b.h, q); }
    }
    PRIO0();
    acc = p + q;

    split5<LIMBS>(acc, hi, C0, C1);
    PRIO1();
    if (LIMBS >= 2) {
        p = MFMA(LF[21 * 64 + lane], C0.h, Z);
        q = MFMA(LF[22 * 64 + lane], C1.h, Z);
        p = MFMA(LF[23 * 64 + lane], C0.h, p);
        q = MFMA(LF[24 * 64 + lane], C1.h, q);
        if (LIMBS == 3) { p = MFMA(LF[25 * 64 + lane], C0.h, p); q = MFMA(LF[26 * 64 + lane], C1.h, q); }
        acc = p + q;
    } else {
        acc = MFMA(LF[21 * 64 + lane], C0.h, Z);
    }
    PRIO0();

    return acc;
}

// Fused body: hedge(step i) [LIMBS=1, tT=th0] and lev(step i+1) [LIMBS=3,
// tT=tl*] — mutually independent (both depend only on the current price).
// Each chain is op-for-op identical to its r21 evalnet5 instantiation;
// they share the price/f3 splits and the LF3/4/15/16 LDS reads.
__device__ __forceinline__ void evalnet_fused(
    unsigned pf0, unsigned pf1, unsigned pf2, unsigned th0,
    unsigned tl0, unsigned tl1, unsigned tl2,
    bool hi, const bf16x8* LF, int lane, const f32x16& Z,
    f32x16& outH, f32x16& outL)
{
    B8 Bh, Bl;
    if (!hi) {
        Bh.u[0] = pf0; Bh.u[1] = th0; Bh.u[2] = 0u;          Bh.u[3] = 0u;
        Bl.u[0] = pf0; Bl.u[1] = tl0; Bl.u[2] = pf2;         Bl.u[3] = tl2;
    } else {
        Bh.u[0] = 0u;  Bh.u[1] = 0u;  Bh.u[2] = 0x00003F80u; Bh.u[3] = 0u;
        Bl.u[0] = pf1; Bl.u[1] = tl1; Bl.u[2] = 0x00003F80u; Bl.u[3] = 0u;
    }

    PRIO1();
    f32x16 ah = MFMA(LF[0 * 64 + lane], Bh.h, Z);
    f32x16 al = MFMA(LF[0 * 64 + lane], Bl.h, Z);
    al = MFMA(LF[1 * 64 + lane], Bl.h, al);
    al = MFMA(LF[2 * 64 + lane], Bl.h, al);
    PRIO0();

    B8 H0a, H0b, Hd1, Hd2, Hd3, Hd4, Hc0, Hc1;
    B8 L0a, L0b, L1a, L1b, L2a, L2b, Lc0, Lc1;
    f32x16 p, q, ph, qh;

    // L2
    split30<1>(ah, hi, H0a, H0b, Hd1, Hd2, Hd3, Hd4);
    split30<3>(al, hi, L0a, L0b, L1a, L1b, L2a, L2b);
    PRIO1();
    ph = MFMA(LF[3 * 64 + lane], H0a.h, Z);
    qh = MFMA(LF[4 * 64 + lane], H0b.h, Z);
    p = MFMA(LF[3 * 64 + lane], L0a.h, Z);
    q = MFMA(LF[4 * 64 + lane], L0b.h, Z);
    p = MFMA(LF[3 * 64 + lane], L1a.h, p);
    q = MFMA(LF[4 * 64 + lane], L1b.h, q);
    p = MFMA(LF[3 * 64 + lane], L2a.h, p);
    q = MFMA(LF[4 * 64 + lane], L2b.h, q);
    p = MFMA(LF[5 * 64 + lane], L0a.h, p);
    q = MFMA(LF[6 * 64 + lane], L0b.h, q);
    p = MFMA(LF[5 * 64 + lane], L1a.h, p);
    q = MFMA(LF[6 * 64 + lane], L1b.h, q);
    p = MFMA(LF[7 * 64 + lane], L0a.h, p);
    q = MFMA(LF[8 * 64 + lane], L0b.h, q);
    PRIO0();
    ah = ph + qh;
    al = p + q;

    // L3
    split5<1>(ah, hi, Hc0, Hc1);
    split5<3>(al, hi, Lc0, Lc1);
    PRIO1();
    ah = MFMA(LF[9 * 64 + lane], Hc0.h, Z);
    p = MFMA(LF[9 * 64 + lane], Lc0.h, Z);
    q = MFMA(LF[10 * 64 + lane], Lc1.h, Z);
    p = MFMA(LF[11 * 64 + lane], Lc0.h, p);
    q = MFMA(LF[12 * 64 + lane], Lc1.h, q);
    p = MFMA(LF[13 * 64 + lane], Lc0.h, p);
    q = MFMA(LF[14 * 64 + lane], Lc1.h, q);
    PRIO0();
    al = p + q;

    // L4
    split30<1>(ah, hi, H0a, H0b, Hd1, Hd2, Hd3, Hd4);
    split30<3>(al, hi, L0a, L0b, L1a, L1b, L2a, L2b);
    PRIO1();
    ph = MFMA(LF[15 * 64 + lane], H0a.h, Z);
    qh = MFMA(LF[16 * 64 + lane], H0b.h, Z);
    p = MFMA(LF[15 * 64 + lane], L0a.h, Z);
    q = MFMA(LF[16 * 64 + lane], L0b.h, Z);
    p = MFMA(LF[15 * 64 + lane], L1a.h, p);
    q = MFMA(LF[16 * 64 + lane], L1b.h, q);
    p = MFMA(LF[15 * 64 + lane], L2a.h, p);
    q = MFMA(LF[16 * 64 + lane], L2b.h, q);
    p = MFMA(LF[17 * 64 + lane], L0a.h, p);
    q = MFMA(LF[18 * 64 + lane], L0b.h, q);
    p = MFMA(LF[17 * 64 + lane], L1a.h, p);
    q = MFMA(LF[18 * 64 + lane], L1b.h, q);
    p = MFMA(LF[19 * 64 + lane], L0a.h, p);
    q = MFMA(LF[20 * 64 + lane], L0b.h, q);
    PRIO0();
    ah = ph + qh;
    al = p + q;

    // L5
    split5<1>(ah, hi, Hc0, Hc1);
    split5<3>(al, hi, Lc0, Lc1);
    PRIO1();
    ah = MFMA(LF[21 * 64 + lane], Hc0.h, Z);
    p = MFMA(LF[21 * 64 + lane], Lc0.h, Z);
    q = MFMA(LF[22 * 64 + lane], Lc1.h, Z);
    p = MFMA(LF[23 * 64 + lane], Lc0.h, p);
    q = MFMA(LF[24 * 64 + lane], Lc1.h, q);
    p = MFMA(LF[25 * 64 + lane], Lc0.h, p);
    q = MFMA(LF[26 * 64 + lane], Lc1.h, q);
    PRIO0();
    al = p + q;

    outH = ah;
    outL = al;
}

// L6 column-COL dot on f32 VALU (wave-uniform W6 reads -> s_loads); r21 exact.
template<int COL>
__device__ __forceinline__ float l6dot(const f32x16& a5v, bool hi, const float* __restrict__ W6)
{
    float part = 0.f;
    if (!hi) {
#pragma unroll
        for (int r = 0; r < 16; ++r) {
            const int row = (r & 3) + 8 * (r >> 2);
            part = fmaf(fmaxf(a5v[r], 0.f), W6[row * 2 + COL], part);
        }
    } else {
#pragma unroll
        for (int r = 0; r < 16; ++r) {
            const int row = (r & 3) + 8 * (r >> 2) + 4;
            if (row < 30) part = fmaf(fmaxf(a5v[r], 0.f), W6[row * 2 + COL], part);
        }
    }
    part += __shfl_xor(part, 32);
    return part;
}

// ---------- partition: block-aggregated (2 atomics/block) — validated r18 ----------
__global__ __launch_bounds__(1024) void partition_kernel(
    const float* __restrict__ Tv, int* __restrict__ ws, int Btot)
{
    __shared__ int cntA[16], cntB[16], baseSh[2];
    const int tid = threadIdx.x;
    const int wid = tid >> 6;
    const int lane = tid & 63;
    const int i = blockIdx.x * 1024 + tid;
    const bool valid = i < Btot;
    const bool isLong  = valid && (Tv[valid ? i : 0] > 0.75f);
    const bool isShort = valid && !isLong;
    const unsigned long long mA = __ballot(isLong);
    const unsigned long long mB = __ballot(isShort);
    const unsigned long long ltm = (1ull << lane) - 1ull;

    if (lane == 0) { cntA[wid] = __popcll(mA); cntB[wid] = __popcll(mB); }
    __syncthreads();
    if (tid == 0) {
        int ta = 0, tb = 0;
#pragma unroll
        for (int k = 0; k < 16; ++k) {
            const int a = cntA[k]; cntA[k] = ta; ta += a;
            const int b = cntB[k]; cntB[k] = tb; tb += b;
        }
        baseSh[0] = ta ? atomicAdd(&ws[0], ta) : 0;
        baseSh[1] = tb ? atomicAdd(&ws[1], tb) : 0;
    }
    __syncthreads();

    int* list = ws + 16;
    if (isLong) {
        const int pos = baseSh[0] + cntA[wid] + __popcll(mA & ltm);
        list[pos] = i;
    }
    if (isShort) {
        const int pos = baseSh[1] + cntB[wid] + __popcll(mB & ltm);
        list[Btot - 1 - pos] = i;
    }
}

// ---------- main compute kernel: r21 + software-pipelined hedge||lev ----------
// Rotation: prologue lev(0); iteration i runs hedge(i) || lev(i+1) fused
// (independent: both depend only on price_{i+1}); epilogue hedge(last).
// Shares the per-price log+3-limb split between the two evals (same bits
// as r21 computed them separately) -> bit-identical output.
template<int LIST>
__global__ __launch_bounds__(256) __attribute__((amdgpu_waves_per_eu(3, 8)))
void mc_hedge_mfma(
    const float* __restrict__ S0, const float* __restrict__ Kv,
    const float* __restrict__ Tv, const float* __restrict__ BM,
    const float* __restrict__ W1, const float* __restrict__ b1,
    const float* __restrict__ W2, const float* __restrict__ b2,
    const float* __restrict__ W3, const float* __restrict__ b3,
    const float* __restrict__ W4, const float* __restrict__ b4,
    const float* __restrict__ W5, const float* __restrict__ b5,
    const float* __restrict__ W6, const float* __restrict__ b6,
    const int* __restrict__ list, float* __restrict__ out, int Btot)
{
    __shared__ bf16x8 LFs[NFRAG * 64];

    const int lane = threadIdx.x & 63;
    const int wid  = threadIdx.x >> 6;

    if (wid == 0) {
        LFs[0 * 64 + lane]  = a1f<0>(W1, b1, lane);
        LFs[1 * 64 + lane]  = a1f<1>(W1, b1, lane);
        LFs[2 * 64 + lane]  = a1f<2>(W1, b1, lane);
        LFs[3 * 64 + lane]  = awide<0,0>(W2, b2, 5, 5, lane);
        LFs[4 * 64 + lane]  = awide<1,0>(W2, b2, 5, 5, lane);
        LFs[5 * 64 + lane]  = awide<0,1>(W2, b2, 5, 5, lane);
        LFs[6 * 64 + lane]  = awide<1,1>(W2, b2, 5, 5, lane);
        LFs[7 * 64 + lane]  = awide<0,2>(W2, b2, 5, 5, lane);
        LFs[8 * 64 + lane]  = awide<1,2>(W2, b2, 5, 5, lane);
        LFs[9 * 64 + lane]  = a5<0,0>(W3, b3, lane);
        LFs[10 * 64 + lane] = a5<0,1>(W3, b3, lane);
        LFs[11 * 64 + lane] = a5<1,0>(W3, b3, lane);
        LFs[12 * 64 + lane] = a5<1,1>(W3, b3, lane);
        LFs[13 * 64 + lane] = a5<2,0>(W3, b3, lane);
        LFs[14 * 64 + lane] = a5<2,1>(W3, b3, lane);
        LFs[15 * 64 + lane] = awide<0,0>(W4, b4, 5, 5, lane);
        LFs[16 * 64 + lane] = awide<1,0>(W4, b4, 5, 5, lane);
        LFs[17 * 64 + lane] = awide<0,1>(W4, b4, 5, 5, lane);
        LFs[18 * 64 + lane] = awide<1,1>(W4, b4, 5, 5, lane);
        LFs[19 * 64 + lane] = awide<0,2>(W4, b4, 5, 5, lane);
        LFs[20 * 64 + lane] = awide<1,2>(W4, b4, 5, 5, lane);
        LFs[21 * 64 + lane] = a5<0,0>(W5, b5, lane);
        LFs[22 * 64 + lane] = a5<0,1>(W5, b5, lane);
        LFs[23 * 64 + lane] = a5<1,0>(W5, b5, lane);
        LFs[24 * 64 + lane] = a5<1,1>(W5, b5, lane);
        LFs[25 * 64 + lane] = a5<2,0>(W5, b5, lane);
        LFs[26 * 64 + lane] = a5<2,1>(W5, b5, lane);
    }
    __syncthreads();
    const bf16x8* LF = LFs;

    const int base = blockIdx.x * 128 + wid * 32;   // 32 paths per wave
    if (base >= Btot) return;
    const int li = min(base + (lane & 31), Btot - 1);
    const int p = LIST ? list[li] : li;
    const bool hi = lane >= 32;

    const float b60 = b6[0], b61 = b6[1];

    f32x16 Z;
#pragma unroll
    for (int i = 0; i < 16; ++i) Z[i] = 0.0f;

    float price = S0[p];
    const float Kk = Kv[p];
    const float T  = Tv[p];
    const float logK = __logf(Kk);
    float hedge = 0.0f;
    const float* bmrow = BM + (size_t)p * NSTEPS;

    int wsteps = NSTEPS;
    if (LIST) {
        const int st = (T > 0.75f) ? NSTEPS : (NSTEPS / 2);
        wsteps = __shfl(st, 0);
    }

    // carried tT limbs for the NEXT hedge (step idx); ct0 is all hedge needs.
    unsigned ct0, ct1, ct2;

    // ---- prologue: lev(0) ----
    {
        const float time0 = (float)1 / (float)NSTEPS;
        const float tmt0 = T - time0;
        split_pair<3>(time0, tmt0, ct0, ct1, ct2);
        const float dc0 = (time0 <= T) ? 1.0f : 0.0f;
        const float inc0 = bmrow[0] * (1.0f / (float)NSTEPS);
        float f3 = __logf(price) - logK;
        f32x16 a = evalnet5<3>(price, f3, ct0, ct1, ct2, hi, LF, lane, Z);
        const float lev = l6dot<0>(a, hi, W6) + b60;
        price = price + dc0 * lev * price * inc0;
    }

    // ---- fused steady state: hedge(idx) || lev(idx+1) ----
#pragma unroll 1
    for (int idx = 0; idx < wsteps - 1; ++idx) {
        const float timeH = (float)(idx + 1) / (float)NSTEPS;   // exact
        const float timeL = (float)(idx + 2) / (float)NSTEPS;
        const float dcH = (timeH <= T) ? 1.0f : 0.0f;
        const float dcL = (timeL <= T) ? 1.0f : 0.0f;
        const float incH = bmrow[idx] * (1.0f / (float)NSTEPS);
        const float incL = bmrow[idx + 1] * (1.0f / (float)NSTEPS);
        const float tmtL = T - timeL;

        unsigned nl0, nl1, nl2;
        split_pair<3>(timeL, tmtL, nl0, nl1, nl2);

        const float f3 = __logf(price) - logK;
        unsigned pf0, pf1, pf2;
        split_pair<3>(price, f3, pf0, pf1, pf2);

        f32x16 aH, aL;
        evalnet_fused(pf0, pf1, pf2, ct0, nl0, nl1, nl2, hi, LF, lane, Z, aH, aL);

        const float hed = (l6dot<1>(aH, hi, W6) + b61) * incH;
        hedge = hedge + dcH * hed;

        const float lev = l6dot<0>(aL, hi, W6) + b60;
        price = price + dcL * lev * price * incL;

        ct0 = nl0;
    }

    // ---- epilogue: hedge(wsteps-1) ----
    {
        const int idx = wsteps - 1;
        const float timeH = (float)(idx + 1) / (float)NSTEPS;
        const float dcH = (timeH <= T) ? 1.0f : 0.0f;
        const float incH = bmrow[idx] * (1.0f / (float)NSTEPS);
        const float f3 = __logf(price) - logK;
        f32x16 aH = evalnet5<1>(price, f3, ct0, 0u, 0u, hi, LF, lane, Z);
        const float hed = (l6dot<1>(aH, hi, W6) + b61) * incH;
        hedge = hedge + dcH * hed;
    }

    if (!hi && (base + lane) < Btot) {
        const float payoff = fmaxf(price - Kk, 0.0f);
        out[p] = payoff - hedge;
    }
}

extern "C" void kernel_launch(void* const* d_in, const int* in_sizes, int n_in,
                              void* d_out, int out_size, void* d_ws, size_t ws_size,
                              hipStream_t stream)
{
    const float* S0 = (const float*)d_in[0];
    const float* Kv = (const float*)d_in[1];
    const float* Tv = (const float*)d_in[2];
    const float* BM = (const float*)d_in[3];
    const float* W1 = (const float*)d_in[4];
    const float* b1 = (const float*)d_in[5];
    const float* W2 = (const float*)d_in[6];
    const float* b2 = (const float*)d_in[7];
    const float* W3 = (const float*)d_in[8];
    const float* b3 = (const float*)d_in[9];
    const float* W4 = (const float*)d_in[10];
    const float* b4 = (const float*)d_in[11];
    const float* W5 = (const float*)d_in[12];
    const float* b5 = (const float*)d_in[13];
    const float* W6 = (const float*)d_in[14];
    const float* b6 = (const float*)d_in[15];

    float* out = (float*)d_out;
    const int B = in_sizes[0];
    const int gridC = (B + 127) / 128;
    const size_t need = (size_t)(16 + B) * sizeof(int);

    if (ws_size >= need) {
        int* ws = (int*)d_ws;
        hipMemsetAsync(ws, 0, 16 * sizeof(int), stream);
        partition_kernel<<<(B + 1023) / 1024, 1024, 0, stream>>>(Tv, ws, B);
        mc_hedge_mfma<1><<<gridC, 256, 0, stream>>>(
            S0, Kv, Tv, BM, W1, b1, W2, b2, W3, b3, W4, b4, W5, b5, W6, b6,
            ws + 16, out, B);
    } else {
        mc_hedge_mfma<0><<<gridC, 256, 0, stream>>>(
            S0, Kv, Tv, BM, W1, b1, W2, b2, W3, b3, W4, b4, W5, b5, W6, b6,
            (const int*)nullptr, out, B);
    }
}